// Round 14
// baseline (241.933 us; speedup 1.0000x reference)
//
#include <hip/hip_runtime.h>
#include <hip/hip_bf16.h>
#include <math.h>

#define T_SEQ 2048
#define DM 1024
#define NH 16
#define DH 64
#define CHUNK 64
#define NCHUNK (T_SEQ / CHUNK)   // 32

typedef __hip_bfloat16 bf16;
typedef __attribute__((ext_vector_type(8))) short short8;
typedef __attribute__((ext_vector_type(4))) short short4v;
typedef __attribute__((ext_vector_type(4))) float f32x4;

static __device__ __forceinline__ short f2b_bits(float f) {
  bf16 t = __float2bfloat16(f);
  short s;
  __builtin_memcpy(&s, &t, 2);
  return s;
}
static __device__ __forceinline__ float b2f(short s) {
  unsigned int u = ((unsigned int)(unsigned short)s) << 16;
  float f;
  __builtin_memcpy(&f, &u, 4);
  return f;
}
// gated ELU+1: elu(x)+1 = x>0 ? x+1 : exp(x)
static __device__ __forceinline__ float gelu1(float raw, float gate, float inv) {
  float x = raw * gate * inv;
  return x > 0.f ? x + 1.f : __expf(x);
}
static __device__ __forceinline__ void gload16(const void* g, void* l) {
  __builtin_amdgcn_global_load_lds((const __attribute__((address_space(1))) void*)g,
                                   (__attribute__((address_space(3))) void*)l, 16, 0, 0);
}

// ---------------------------------------------------------------------------
// prep: blocks 0..2047 = LayerNorm rows (blocks 0..7 also zero gate_accum;
//       block 0 zeroes hcnt); blocks 2048.. = fp32->bf16 weight conversion.
// ---------------------------------------------------------------------------
#define PREP_WBLOCKS (5 * DM * DM / 4 / 256)   // 5120
__global__ __launch_bounds__(256) void prep_kernel(
    const float* __restrict__ x, const float* __restrict__ g,
    const float* __restrict__ b, const float* __restrict__ qkv_w,
    const float* __restrict__ gate_w, const float* __restrict__ proj_w,
    bf16* __restrict__ xn, bf16* __restrict__ xbf,
    bf16* __restrict__ wqkv, bf16* __restrict__ wgate, bf16* __restrict__ wproj,
    float* __restrict__ gate_accum, int* __restrict__ hcnt) {
  const int blk = blockIdx.x;
  if (blk < T_SEQ) {
    const int row = blk;
    if (row < 8) gate_accum[row * 256 + threadIdx.x] = 0.f;
    if (row == 0 && threadIdx.x < NH) hcnt[threadIdx.x] = 0;
    const float* xr = x + (size_t)row * DM;
    float vals[4];
    float s = 0.f, s2 = 0.f;
#pragma unroll
    for (int i = 0; i < 4; i++) {
      float v = xr[threadIdx.x + i * 256];
      vals[i] = v;
      s += v;
      s2 += v * v;
    }
#pragma unroll
    for (int m = 1; m < 64; m <<= 1) {
      s += __shfl_xor(s, m, 64);
      s2 += __shfl_xor(s2, m, 64);
    }
    __shared__ float red[8];
    const int wid = threadIdx.x >> 6;
    if ((threadIdx.x & 63) == 0) {
      red[wid] = s;
      red[4 + wid] = s2;
    }
    __syncthreads();
    s = red[0] + red[1] + red[2] + red[3];
    s2 = red[4] + red[5] + red[6] + red[7];
    const float mean = s * (1.f / DM);
    const float var = s2 * (1.f / DM) - mean * mean;
    const float rstd = rsqrtf(var + 1e-5f);
#pragma unroll
    for (int i = 0; i < 4; i++) {
      int idx = threadIdx.x + i * 256;
      float v = (vals[i] - mean) * rstd * g[idx] + b[idx];
      xn[(size_t)row * DM + idx] = __float2bfloat16(v);
      xbf[(size_t)row * DM + idx] = __float2bfloat16(vals[i]);
    }
  } else {
    constexpr int NQ = 3 * DM * DM / 4, NS = DM * DM / 4;
    int i = (blk - T_SEQ) * 256 + threadIdx.x;
    const float* src;
    bf16* dst;
    int j;
    if (i < NQ) { src = qkv_w; dst = wqkv; j = i; }
    else if (i < NQ + NS) { src = gate_w; dst = wgate; j = i - NQ; }
    else { src = proj_w; dst = wproj; j = i - NQ - NS; }
    float4 v = ((const float4*)src)[j];
    short4v sv;
    sv.x = f2b_bits(v.x); sv.y = f2b_bits(v.y); sv.z = f2b_bits(v.z); sv.w = f2b_bits(v.w);
    *(short4v*)&dst[j * 4] = sv;
  }
}

// ---------------------------------------------------------------------------
// Fused gate+qkv GEMM. R23 config (confirmed win): 128x128 tile, BK=128,
// 8 K-steps, LDS 2x32KB, 2 blocks/CU. Swizzle: slot s of row r holds chunk
// s^(r&15).
// ---------------------------------------------------------------------------
__global__ __launch_bounds__(256) void gemm_gateqkv(
    const bf16* __restrict__ xbf, const bf16* __restrict__ xn,
    const bf16* __restrict__ wg, const bf16* __restrict__ wq,
    const float* __restrict__ gate_b, const float* __restrict__ qkv_b,
    short* __restrict__ Gb, float* __restrict__ gate_accum,
    short* __restrict__ Qb, short* __restrict__ Kb, short* __restrict__ Vb,
    short* __restrict__ VbT) {
  constexpr int K = 1024;
  __shared__ __align__(16) short As[128 * 128];   // 32 KB
  __shared__ __align__(16) short Bs[128 * 128];   // 32 KB

  const int tid = threadIdx.x;
  const int wid = tid >> 6, lane = tid & 63;
  const int wm = wid >> 1, wn = wid & 1;   // wave tile 64(m) x 64(n)
  const int lm = lane & 15, quad = lane >> 4;

  const int nt = blockIdx.x;
  const bool isGate = nt < 8;
  const int m0 = blockIdx.y * 128;
  const int n0 = (isGate ? nt : nt - 8) * 128;
  const short* Ag = (const short*)(isGate ? xbf : xn);
  const short* Wg = (const short*)(isGate ? wg : wq);

  f32x4 zero = {0.f, 0.f, 0.f, 0.f};
  f32x4 acc[4][4];
#pragma unroll
  for (int i = 0; i < 4; i++)
#pragma unroll
    for (int j = 0; j < 4; j++) acc[i][j] = zero;

  // staging: per issue, 256 lanes x 16 B = 4 KB = 16 rows x 256 B.
  const int grow = tid >> 4;
  const int swq = ((tid & 15) ^ ((tid >> 4) & 15)) * 8;

  for (int kb = 0; kb < K; kb += 128) {
    __syncthreads();
#pragma unroll
    for (int it = 0; it < 8; it++) {
      const int row = it * 16 + grow;
      gload16(&Ag[(size_t)(m0 + row) * K + kb + swq], &As[it * 2048 + wid * 512]);
      gload16(&Wg[(size_t)(n0 + row) * K + kb + swq], &Bs[it * 2048 + wid * 512]);
    }
    __syncthreads();
#pragma unroll
    for (int sec = 0; sec < 4; sec++) {
      const int slot8 = (((sec * 4 + quad) ^ lm) * 8);
      short8 afr[4], bfr[4];
#pragma unroll
      for (int i = 0; i < 4; i++)
        afr[i] = *(const short8*)&As[(wm * 64 + i * 16 + lm) * 128 + slot8];
#pragma unroll
      for (int j = 0; j < 4; j++)
        bfr[j] = *(const short8*)&Bs[(wn * 64 + j * 16 + lm) * 128 + slot8];
#pragma unroll
      for (int i = 0; i < 4; i++)
#pragma unroll
        for (int j = 0; j < 4; j++)
          acc[i][j] = __builtin_amdgcn_mfma_f32_16x16x32_bf16(afr[i], bfr[j], acc[i][j], 0, 0, 0);
    }
  }

  // epilogue: C/D layout col = lane&15, row = quad*4 + r
  if (isGate) {
    float* red = (float*)As;   // 128 rows x 32 slots = 16 KB (fits in 32 KB As)
    __syncthreads();           // all waves' MFMA LDS reads done -> reuse As
#pragma unroll
    for (int i = 0; i < 4; i++) {
#pragma unroll
      for (int r = 0; r < 4; r++) {
        const int rowl = wm * 64 + i * 16 + quad * 4 + r;
        const int row = m0 + rowl;
        float rp = 0.f;
#pragma unroll
        for (int j = 0; j < 4; j++) {
          const int col = n0 + wn * 64 + j * 16 + lm;
          float v = acc[i][j][r] + gate_b[col];
          float sig = 1.f / (1.f + __expf(-v));
          Gb[(size_t)row * DM + col] = f2b_bits(sig);
          rp += sig;
        }
        red[rowl * 32 + wn * 16 + lm] = rp;
      }
    }
    __syncthreads();
    if (tid < 128) {
      float s = 0.f;
#pragma unroll
      for (int t2 = 0; t2 < 32; t2++) s += red[tid * 32 + t2];
      atomicAdd(&gate_accum[m0 + tid], s);
    }
  } else {
#pragma unroll
    for (int i = 0; i < 4; i++) {
      const int rbase = m0 + wm * 64 + i * 16 + quad * 4;
#pragma unroll
      for (int j = 0; j < 4; j++) {
        const int col = n0 + wn * 64 + j * 16 + lm;
        const float bval = qkv_b[col];
#pragma unroll
        for (int r = 0; r < 4; r++) {
          const int row = rbase + r;
          const short bv = f2b_bits(acc[i][j][r] + bval);
          if (col < DM) {
            const int d = col;
            Qb[((size_t)(d >> 6) * T_SEQ + row) * DH + (d & 63)] = bv;
          } else if (col < 2 * DM) {
            const int d = col - DM;
            Kb[((size_t)(d >> 6) * T_SEQ + row) * DH + (d & 63)] = bv;
          } else {
            const int d = col - 2 * DM;
            Vb[((size_t)(d >> 6) * T_SEQ + row) * DH + (d & 63)] = bv;
            VbT[((size_t)(d >> 6) * DH + (d & 63)) * T_SEQ + row] = bv;
          }
        }
      }
    }
  }
}

// ---------------------------------------------------------------------------
// Pass A + fused scan (R25): per (h,c) RAW chunk sums -> SkvT/Sk; then each
// block release-fences and bumps hcnt[h] (device-scope atomic -- primitive
// validated in R21); the block seeing old==NCHUNK-1 acquire-fences and
// performs head h's exclusive prefix scan in place (identical fp32
// sequential order as the old scan_excl kernel -> bit-identical numerics).
// No spinning, no co-residency requirement: the last block runs after the
// others have FINISHED. Removes one kernel launch (~12-16us of wall).
// ---------------------------------------------------------------------------
__global__ __launch_bounds__(256, 2) void chunk_sum_mm(const short* __restrict__ Kb,
                                                       const short* __restrict__ Gb,
                                                       const float* __restrict__ ga,
                                                       const short* __restrict__ Vb,
                                                       float* __restrict__ SkvT,
                                                       float* __restrict__ Sk,
                                                       int* __restrict__ hcnt) {
  constexpr int STR = 68;
  __shared__ __align__(16) float Ks2[64 * STR];
  __shared__ __align__(16) float Vs2[64 * STR];
  const int b = blockIdx.x;
  const int h = b >> 5, c = b & 31;
  const int tid = threadIdx.x;
  const int ty = tid >> 4, tx = tid & 15;
  const int d0 = ty * 4, m0 = tx * 4;
  const int t0 = c * CHUNK;
  const size_t cb = ((size_t)h * T_SEQ + t0) * DH;
#pragma unroll
  for (int p = 0; p < 4; p++) {
    int f = p * 256 + tid, row = f >> 4, seg = (f & 15) * 4;
    const int t = t0 + row;
    short4v kr = *(const short4v*)&Kb[cb + row * 64 + seg];
    short4v gr = *(const short4v*)&Gb[(size_t)t * DM + h * 64 + seg];
    short4v vr = *(const short4v*)&Vb[cb + row * 64 + seg];
    const float inv = 1.f / (ga[t] * (1.f / DM) + 1e-5f);
    f32x4 kgv, vv;
#pragma unroll
    for (int e = 0; e < 4; e++) {
      kgv[e] = gelu1(b2f(kr[e]), b2f(gr[e]), inv);
      vv[e] = b2f(vr[e]);
    }
    *(f32x4*)&Ks2[row * STR + seg] = kgv;
    *(f32x4*)&Vs2[row * STR + seg] = vv;
  }
  __syncthreads();
  float acc[4][4] = {};
#pragma unroll 4
  for (int s = 0; s < 64; s++) {
    f32x4 kf = *(const f32x4*)&Ks2[s * STR + d0];
    f32x4 vf = *(const f32x4*)&Vs2[s * STR + m0];
#pragma unroll
    for (int i = 0; i < 4; i++)
#pragma unroll
      for (int j = 0; j < 4; j++) acc[i][j] += kf[i] * vf[j];
  }
  float* outp = SkvT + (size_t)b * 4096;
  // transposed store: SkvT[m][d] = acc[d][m]
#pragma unroll
  for (int i = 0; i < 4; i++)
#pragma unroll
    for (int j = 0; j < 4; j++)
      outp[(m0 + j) * 64 + (d0 + i)] = acc[i][j];
  if (tid < 64) {
    float ss = 0.f;
#pragma unroll 4
    for (int s = 0; s < 64; s++) ss += Ks2[s * STR + tid];
    Sk[b * 64 + tid] = ss;
  }

  // ---- last-block-per-head exclusive scan (replaces scan_excl) ----
  __threadfence();             // release this block's SkvT/Sk writes
  __syncthreads();             // all threads fenced before the signal
  __shared__ int lastFlag;
  if (tid == 0) {
    int old = atomicAdd(&hcnt[h], 1);      // device-scope (G12)
    lastFlag = (old == NCHUNK - 1) ? 1 : 0;
  }
  __syncthreads();
  if (lastFlag) {
    __threadfence();           // acquire: see all other blocks' writes
    float* baseh = SkvT + (size_t)h * NCHUNK * 4096;
#pragma unroll 1
    for (int pass = 0; pass < 4; pass++) {
      const int e = pass * 1024 + tid * 4;
      // two register-preloaded halves (16 x f32x4 each) with carried run
      f32x4 run = {0.f, 0.f, 0.f, 0.f};
#pragma unroll 1
      for (int half = 0; half < 2; half++) {
        f32x4 v[16];
#pragma unroll
        for (int cc = 0; cc < 16; cc++)
          v[cc] = *(const f32x4*)&baseh[(size_t)(half * 16 + cc) * 4096 + e];
#pragma unroll
        for (int cc = 0; cc < 16; cc++) {
          *(f32x4*)&baseh[(size_t)(half * 16 + cc) * 4096 + e] = run;
#pragma unroll
          for (int q2 = 0; q2 < 4; q2++) run[q2] += v[cc][q2];
        }
      }
    }
    if (tid < 64) {
      float* bs = Sk + (size_t)h * NCHUNK * 64 + tid;
      float vv[NCHUNK];
#pragma unroll
      for (int cc = 0; cc < NCHUNK; cc++) vv[cc] = bs[cc * 64];
      float run = 0.f;
#pragma unroll
      for (int cc = 0; cc < NCHUNK; cc++) {
        bs[cc * 64] = run;
        run += vv[cc];
      }
    }
  }
}

// ---------------------------------------------------------------------------
// Pass C (MFMA): per (h,c), 4 waves.
//   S = Qg.Kg^T; O^T = P^T.Qg^T + V^T.S^T; den from masked-S rowsum + q.skp.
// R13: invden dot product parallelized across all 256 threads.
// ---------------------------------------------------------------------------
__global__ __launch_bounds__(256, 2) void attn_mfma(const short* __restrict__ Qb,
                                                    const short* __restrict__ Kb,
                                                    const short* __restrict__ Gb,
                                                    const float* __restrict__ ga,
                                                    const short* __restrict__ VbT,
                                                    const float* __restrict__ SkvT,
                                                    const float* __restrict__ Sk,
                                                    bf16* __restrict__ O) {
  constexpr int STR = 72;
  __shared__ __align__(16) short Qs[64 * STR];
  __shared__ __align__(16) short Ks[64 * STR];
  __shared__ __align__(16) short Vt[64 * STR];
  __shared__ __align__(16) short Pt[64 * STR];
  __shared__ __align__(16) short SL[64 * STR];
  __shared__ float denp[64], invden[64], skp[64];
  const int b = blockIdx.x;
  const int h = b >> 5, c = b & 31;
  const int tid = threadIdx.x;
  const int wid = tid >> 6, lane = tid & 63;
  const int lm = lane & 15, quad = lane >> 4;
  const int t0 = c * CHUNK;
  const size_t cb = ((size_t)h * T_SEQ + t0) * DH;
  const float* Pg = SkvT + (size_t)b * 4096;

#pragma unroll
  for (int p = 0; p < 4; p++) {
    const int f = p * 256 + tid, row = f >> 4, seg = (f & 15) * 4;
    const int t = t0 + row;
    short4v qr = *(const short4v*)&Qb[cb + row * 64 + seg];
    short4v kr = *(const short4v*)&Kb[cb + row * 64 + seg];
    short4v gr = *(const short4v*)&Gb[(size_t)t * DM + h * 64 + seg];
    short4v vtr = *(const short4v*)&VbT[((size_t)h * DH + row) * T_SEQ + t0 + seg];
    f32x4 pr = *(const f32x4*)&Pg[row * 64 + seg];
    const float inv = 1.f / (ga[t] * (1.f / DM) + 1e-5f);
    short4v qs, ks, ps;
#pragma unroll
    for (int e = 0; e < 4; e++) {
      qs[e] = f2b_bits(gelu1(b2f(qr[e]), b2f(gr[e]), inv));
      ks[e] = f2b_bits(gelu1(b2f(kr[e]), b2f(gr[e]), inv));
      ps[e] = f2b_bits(pr[e]);
    }
    *(short4v*)&Qs[row * STR + seg] = qs;
    *(short4v*)&Ks[row * STR + seg] = ks;
    *(short4v*)&Vt[row * STR + seg] = vtr;
    *(short4v*)&Pt[row * STR + seg] = ps;
  }
  if (tid < 64) skp[tid] = Sk[b * 64 + tid];
  __syncthreads();  // B1

  f32x4 zero = {0.f, 0.f, 0.f, 0.f};
  // ---- S = Qg.Kg^T ----
  short8 aq[2];
#pragma unroll
  for (int ks = 0; ks < 2; ks++)
    aq[ks] = *(const short8*)&Qs[(wid * 16 + lm) * STR + ks * 32 + quad * 8];
  f32x4 accs[4];
#pragma unroll
  for (int j = 0; j < 4; j++) accs[j] = zero;
#pragma unroll
  for (int j = 0; j < 4; j++)
#pragma unroll
    for (int ks = 0; ks < 2; ks++) {
      short8 bk = *(const short8*)&Ks[(j * 16 + lm) * STR + ks * 32 + quad * 8];
      accs[j] = __builtin_amdgcn_mfma_f32_16x16x32_bf16(aq[ks], bk, accs[j], 0, 0, 0);
    }
  float rowpart[4] = {0.f, 0.f, 0.f, 0.f};
#pragma unroll
  for (int j = 0; j < 4; j++) {
    const int s = j * 16 + lm;
#pragma unroll
    for (int r = 0; r < 4; r++) {
      const int t = wid * 16 + quad * 4 + r;
      float v = (s <= t) ? accs[j][r] : 0.f;
      accs[j][r] = v;
      rowpart[r] += v;
    }
  }
#pragma unroll
  for (int msk = 1; msk < 16; msk <<= 1)
#pragma unroll
    for (int r = 0; r < 4; r++) rowpart[r] += __shfl_xor(rowpart[r], msk, 64);
  if (lm == 0)
#pragma unroll
    for (int r = 0; r < 4; r++) denp[wid * 16 + quad * 4 + r] = rowpart[r];
#pragma unroll
  for (int j = 0; j < 4; j++)
#pragma unroll
    for (int r = 0; r < 4; r++)
      SL[(wid * 16 + quad * 4 + r) * STR + j * 16 + lm] = f2b_bits(accs[j][r]);

  // ---- O1^T = P^T.Qg^T ----
  f32x4 acco[4];
#pragma unroll
  for (int j = 0; j < 4; j++) acco[j] = zero;
  short8 ap[2];
#pragma unroll
  for (int ks = 0; ks < 2; ks++)
    ap[ks] = *(const short8*)&Pt[(wid * 16 + lm) * STR + ks * 32 + quad * 8];
#pragma unroll
  for (int j = 0; j < 4; j++)
#pragma unroll
    for (int ks = 0; ks < 2; ks++) {
      short8 bq = *(const short8*)&Qs[(j * 16 + lm) * STR + ks * 32 + quad * 8];
      acco[j] = __builtin_amdgcn_mfma_f32_16x16x32_bf16(ap[ks], bq, acco[j], 0, 0, 0);
    }
  __syncthreads();  // B2: SL + denp complete

  {
    // all 256 threads: row = tid>>2, part = tid&3 covers 16 d each
    const int row = tid >> 2, part = tid & 3;
    float s = 0.f;
#pragma unroll
    for (int dd = 0; dd < 16; dd++) {
      const int d = part * 16 + dd;
      s += b2f(Qs[row * STR + d]) * skp[d];
    }
    s += __shfl_xor(s, 1, 64);
    s += __shfl_xor(s, 2, 64);
    if (part == 0) invden[row] = 1.f / (1e-5f + denp[row] + s);
  }

  // ---- O2^T += V^T.S^T ----
  short8 av[2];
#pragma unroll
  for (int ks = 0; ks < 2; ks++)
    av[ks] = *(const short8*)&Vt[(wid * 16 + lm) * STR + ks * 32 + quad * 8];
#pragma unroll
  for (int j = 0; j < 4; j++)
#pragma unroll
    for (int ks = 0; ks < 2; ks++) {
      short8 bs = *(const short8*)&SL[(j * 16 + lm) * STR + ks * 32 + quad * 8];
      acco[j] = __builtin_amdgcn_mfma_f32_16x16x32_bf16(av[ks], bs, acco[j], 0, 0, 0);
    }
  __syncthreads();  // B3: invden ready

#pragma unroll
  for (int j = 0; j < 4; j++) {
    const int t = j * 16 + lm;
    const float idv = invden[t];
    short4v ov;
#pragma unroll
    for (int r = 0; r < 4; r++) ov[r] = f2b_bits(acco[j][r] * idv);
    *(short4v*)&((short*)O)[(size_t)(t0 + t) * DM + h * 64 + wid * 16 + quad * 4] = ov;
  }
}

// ---------------------------------------------------------------------------
// Proj GEMM: tile 64x64, grid (16 n-fast, 32 m) = 512 blocks (2/CU).
// R24 config (confirmed win): BK=256, 4 K-steps, LDS 2x32KB.
// Swizzle for 512B rows: slot s of row r holds chunk s^(r&31).
// ---------------------------------------------------------------------------
__global__ __launch_bounds__(256) void gemm_proj(const bf16* __restrict__ A,
                                                 const bf16* __restrict__ W,
                                                 const float* __restrict__ bias,
                                                 float* __restrict__ Cout) {
  constexpr int K = 1024;
  __shared__ __align__(16) short As[64 * 256];   // 32 KB
  __shared__ __align__(16) short Bs[64 * 256];   // 32 KB

  const int tid = threadIdx.x;
  const int wid = tid >> 6, lane = tid & 63;
  const int wm = wid >> 1, wn = wid & 1;   // wave tile 32x32
  const int lm = lane & 15, quad = lane >> 4;

  const int n0 = blockIdx.x * 64;
  const int m0 = blockIdx.y * 64;
  const short* Ag = (const short*)A;
  const short* Wg = (const short*)W;

  // staging: per issue, 256 lanes x 16 B = 4 KB = 8 rows x 512 B.
  const int grow = tid >> 5;        // 0..7: row within issue
  const int lchunk = tid & 31;      // LDS slot within row

  f32x4 zero = {0.f, 0.f, 0.f, 0.f};
  f32x4 acc[2][2];
#pragma unroll
  for (int i = 0; i < 2; i++)
#pragma unroll
    for (int j = 0; j < 2; j++) acc[i][j] = zero;

  for (int kb = 0; kb < K; kb += 256) {
    __syncthreads();
#pragma unroll
    for (int it = 0; it < 8; it++) {
      const int row = it * 8 + grow;
      const int swq = (lchunk ^ (row & 31)) * 8;   // source chunk for linear slot
      gload16(&Ag[(size_t)(m0 + row) * K + kb + swq], &As[it * 2048 + wid * 512]);
      gload16(&Wg[(size_t)(n0 + row) * K + kb + swq], &Bs[it * 2048 + wid * 512]);
    }
    __syncthreads();
#pragma unroll
    for (int sec = 0; sec < 8; sec++) {
      short8 afr[2], bfr[2];
#pragma unroll
      for (int i = 0; i < 2; i++) {
        const int row = wm * 32 + i * 16 + lm;
        const int slot8 = (((sec * 4 + quad) ^ (row & 31)) * 8);
        afr[i] = *(const short8*)&As[row * 256 + slot8];
      }
#pragma unroll
      for (int j = 0; j < 2; j++) {
        const int row = wn * 32 + j * 16 + lm;
        const int slot8 = (((sec * 4 + quad) ^ (row & 31)) * 8);
        bfr[j] = *(const short8*)&Bs[row * 256 + slot8];
      }
#pragma unroll
      for (int i = 0; i < 2; i++)
#pragma unroll
        for (int j = 0; j < 2; j++)
          acc[i][j] = __builtin_amdgcn_mfma_f32_16x16x32_bf16(afr[i], bfr[j], acc[i][j], 0, 0, 0);
    }
  }
#pragma unroll
  for (int i = 0; i < 2; i++) {
    const int rbase = m0 + wm * 32 + i * 16 + quad * 4;
#pragma unroll
    for (int j = 0; j < 2; j++) {
      const int col = n0 + wn * 32 + j * 16 + lm;
      const float bval = bias[col];
#pragma unroll
      for (int r = 0; r < 4; r++)
        Cout[(size_t)(rbase + r) * DM + col] = acc[i][j][r] + bval;
    }
  }
}

// ---------------------------------------------------------------------------
extern "C" void kernel_launch(void* const* d_in, const int* in_sizes, int n_in,
                              void* d_out, int out_size, void* d_ws, size_t ws_size,
                              hipStream_t stream) {
  (void)in_sizes; (void)n_in; (void)out_size; (void)ws_size;
  const float* x      = (const float*)d_in[0];
  const float* ln_g   = (const float*)d_in[1];
  const float* ln_b   = (const float*)d_in[2];
  const float* qkv_w  = (const float*)d_in[3];
  const float* qkv_b  = (const float*)d_in[4];
  const float* gate_w = (const float*)d_in[5];
  const float* gate_b = (const float*)d_in[6];
  const float* proj_w = (const float*)d_in[7];
  const float* proj_b = (const float*)d_in[8];
  float* out = (float*)d_out;

  char* ws = (char*)d_ws;
  size_t off = 0;
  auto alloc = [&](size_t bytes) {
    void* p = ws + off;
    off += (bytes + 255) & ~(size_t)255;
    return p;
  };
  bf16*  xn       = (bf16*)alloc((size_t)T_SEQ * DM * 2);
  bf16*  xbf      = (bf16*)alloc((size_t)T_SEQ * DM * 2);
  bf16*  wqkv     = (bf16*)alloc((size_t)3 * DM * DM * 2);
  bf16*  wgate    = (bf16*)alloc((size_t)DM * DM * 2);
  bf16*  wproj    = (bf16*)alloc((size_t)DM * DM * 2);
  short* Gb       = (short*)alloc((size_t)T_SEQ * DM * 2);
  float* gate_accum = (float*)alloc((size_t)T_SEQ * 4);
  short* Qb       = (short*)alloc((size_t)T_SEQ * DM * 2);
  short* Kb       = (short*)alloc((size_t)T_SEQ * DM * 2);
  short* Vb       = (short*)alloc((size_t)T_SEQ * DM * 2);
  short* VbT      = (short*)alloc((size_t)T_SEQ * DM * 2);
  bf16*  Obuf     = (bf16*)alloc((size_t)T_SEQ * DM * 2);
  float* SkvT     = (float*)alloc((size_t)NH * NCHUNK * 4096 * 4);
  float* Sk       = (float*)alloc((size_t)NH * NCHUNK * 64 * 4);
  int*   hcnt     = (int*)alloc(NH * sizeof(int));

  prep_kernel<<<T_SEQ + PREP_WBLOCKS, 256, 0, stream>>>(
      x, ln_g, ln_b, qkv_w, gate_w, proj_w, xn, xbf, wqkv, wgate, wproj,
      gate_accum, hcnt);
  gemm_gateqkv<<<dim3(32, 16), 256, 0, stream>>>(xbf, xn, wgate, wqkv, gate_b, qkv_b,
                                                 Gb, gate_accum, Qb, Kb, Vb, VbT);
  chunk_sum_mm<<<NH * NCHUNK, 256, 0, stream>>>(Kb, Gb, gate_accum, Vb, SkvT, Sk, hcnt);
  attn_mfma<<<NH * NCHUNK, 256, 0, stream>>>(Qb, Kb, Gb, gate_accum, VbT, SkvT, Sk, Obuf);
  gemm_proj<<<dim3(16, 32), 256, 0, stream>>>(Obuf, wproj, proj_b, out);
}

// Round 15
// 155.370 us; speedup vs baseline: 1.5571x; 1.5571x over previous
//
#include <hip/hip_runtime.h>
#include <hip/hip_bf16.h>
#include <math.h>

#define T_SEQ 2048
#define DM 1024
#define NH 16
#define DH 64
#define CHUNK 64
#define NCHUNK (T_SEQ / CHUNK)   // 32

typedef __hip_bfloat16 bf16;
typedef __attribute__((ext_vector_type(8))) short short8;
typedef __attribute__((ext_vector_type(4))) short short4v;
typedef __attribute__((ext_vector_type(4))) float f32x4;

static __device__ __forceinline__ short f2b_bits(float f) {
  bf16 t = __float2bfloat16(f);
  short s;
  __builtin_memcpy(&s, &t, 2);
  return s;
}
static __device__ __forceinline__ float b2f(short s) {
  unsigned int u = ((unsigned int)(unsigned short)s) << 16;
  float f;
  __builtin_memcpy(&f, &u, 4);
  return f;
}
// gated ELU+1: elu(x)+1 = x>0 ? x+1 : exp(x)
static __device__ __forceinline__ float gelu1(float raw, float gate, float inv) {
  float x = raw * gate * inv;
  return x > 0.f ? x + 1.f : __expf(x);
}
static __device__ __forceinline__ void gload16(const void* g, void* l) {
  __builtin_amdgcn_global_load_lds((const __attribute__((address_space(1))) void*)g,
                                   (__attribute__((address_space(3))) void*)l, 16, 0, 0);
}

// ---------------------------------------------------------------------------
// prep: blocks 0..2047 = LayerNorm rows (blocks 0..7 also zero gate_accum);
//       blocks 2048..  = fp32->bf16 weight conversion (qkv|gate|proj).
// ---------------------------------------------------------------------------
#define PREP_WBLOCKS (5 * DM * DM / 4 / 256)   // 5120
__global__ __launch_bounds__(256) void prep_kernel(
    const float* __restrict__ x, const float* __restrict__ g,
    const float* __restrict__ b, const float* __restrict__ qkv_w,
    const float* __restrict__ gate_w, const float* __restrict__ proj_w,
    bf16* __restrict__ xn, bf16* __restrict__ xbf,
    bf16* __restrict__ wqkv, bf16* __restrict__ wgate, bf16* __restrict__ wproj,
    float* __restrict__ gate_accum) {
  const int blk = blockIdx.x;
  if (blk < T_SEQ) {
    const int row = blk;
    if (row < 8) gate_accum[row * 256 + threadIdx.x] = 0.f;
    const float* xr = x + (size_t)row * DM;
    float vals[4];
    float s = 0.f, s2 = 0.f;
#pragma unroll
    for (int i = 0; i < 4; i++) {
      float v = xr[threadIdx.x + i * 256];
      vals[i] = v;
      s += v;
      s2 += v * v;
    }
#pragma unroll
    for (int m = 1; m < 64; m <<= 1) {
      s += __shfl_xor(s, m, 64);
      s2 += __shfl_xor(s2, m, 64);
    }
    __shared__ float red[8];
    const int wid = threadIdx.x >> 6;
    if ((threadIdx.x & 63) == 0) {
      red[wid] = s;
      red[4 + wid] = s2;
    }
    __syncthreads();
    s = red[0] + red[1] + red[2] + red[3];
    s2 = red[4] + red[5] + red[6] + red[7];
    const float mean = s * (1.f / DM);
    const float var = s2 * (1.f / DM) - mean * mean;
    const float rstd = rsqrtf(var + 1e-5f);
#pragma unroll
    for (int i = 0; i < 4; i++) {
      int idx = threadIdx.x + i * 256;
      float v = (vals[i] - mean) * rstd * g[idx] + b[idx];
      xn[(size_t)row * DM + idx] = __float2bfloat16(v);
      xbf[(size_t)row * DM + idx] = __float2bfloat16(vals[i]);
    }
  } else {
    constexpr int NQ = 3 * DM * DM / 4, NS = DM * DM / 4;
    int i = (blk - T_SEQ) * 256 + threadIdx.x;
    const float* src;
    bf16* dst;
    int j;
    if (i < NQ) { src = qkv_w; dst = wqkv; j = i; }
    else if (i < NQ + NS) { src = gate_w; dst = wgate; j = i - NQ; }
    else { src = proj_w; dst = wproj; j = i - NQ - NS; }
    float4 v = ((const float4*)src)[j];
    short4v sv;
    sv.x = f2b_bits(v.x); sv.y = f2b_bits(v.y); sv.z = f2b_bits(v.z); sv.w = f2b_bits(v.w);
    *(short4v*)&dst[j * 4] = sv;
  }
}

// ---------------------------------------------------------------------------
// Fused gate+qkv GEMM. R23 (confirmed win): 128x128 tile, BK=128, 8 K-steps.
// Per-K-step barrier drain is a fixed ~800cy cost (R19 PMC arithmetic);
// halving step count 16->8 was the confirmed win (R22 159.5 -> R23 153.3).
// LDS 2x32KB=64KB, 2 blocks/CU (grid-capped). Swizzle for 256B rows:
// slot s of row r holds chunk s^(r&15).
// ---------------------------------------------------------------------------
__global__ __launch_bounds__(256) void gemm_gateqkv(
    const bf16* __restrict__ xbf, const bf16* __restrict__ xn,
    const bf16* __restrict__ wg, const bf16* __restrict__ wq,
    const float* __restrict__ gate_b, const float* __restrict__ qkv_b,
    short* __restrict__ Gb, float* __restrict__ gate_accum,
    short* __restrict__ Qb, short* __restrict__ Kb, short* __restrict__ Vb,
    short* __restrict__ VbT) {
  constexpr int K = 1024;
  __shared__ __align__(16) short As[128 * 128];   // 32 KB
  __shared__ __align__(16) short Bs[128 * 128];   // 32 KB

  const int tid = threadIdx.x;
  const int wid = tid >> 6, lane = tid & 63;
  const int wm = wid >> 1, wn = wid & 1;   // wave tile 64(m) x 64(n)
  const int lm = lane & 15, quad = lane >> 4;

  const int nt = blockIdx.x;
  const bool isGate = nt < 8;
  const int m0 = blockIdx.y * 128;
  const int n0 = (isGate ? nt : nt - 8) * 128;
  const short* Ag = (const short*)(isGate ? xbf : xn);
  const short* Wg = (const short*)(isGate ? wg : wq);

  f32x4 zero = {0.f, 0.f, 0.f, 0.f};
  f32x4 acc[4][4];
#pragma unroll
  for (int i = 0; i < 4; i++)
#pragma unroll
    for (int j = 0; j < 4; j++) acc[i][j] = zero;

  // staging: per issue, 256 lanes x 16 B = 4 KB = 16 rows x 256 B.
  const int grow = tid >> 4;
  const int swq = ((tid & 15) ^ ((tid >> 4) & 15)) * 8;

  for (int kb = 0; kb < K; kb += 128) {
    __syncthreads();
#pragma unroll
    for (int it = 0; it < 8; it++) {
      const int row = it * 16 + grow;
      gload16(&Ag[(size_t)(m0 + row) * K + kb + swq], &As[it * 2048 + wid * 512]);
      gload16(&Wg[(size_t)(n0 + row) * K + kb + swq], &Bs[it * 2048 + wid * 512]);
    }
    __syncthreads();
#pragma unroll
    for (int sec = 0; sec < 4; sec++) {
      const int slot8 = (((sec * 4 + quad) ^ lm) * 8);
      short8 afr[4], bfr[4];
#pragma unroll
      for (int i = 0; i < 4; i++)
        afr[i] = *(const short8*)&As[(wm * 64 + i * 16 + lm) * 128 + slot8];
#pragma unroll
      for (int j = 0; j < 4; j++)
        bfr[j] = *(const short8*)&Bs[(wn * 64 + j * 16 + lm) * 128 + slot8];
#pragma unroll
      for (int i = 0; i < 4; i++)
#pragma unroll
        for (int j = 0; j < 4; j++)
          acc[i][j] = __builtin_amdgcn_mfma_f32_16x16x32_bf16(afr[i], bfr[j], acc[i][j], 0, 0, 0);
    }
  }

  // epilogue: C/D layout col = lane&15, row = quad*4 + r
  if (isGate) {
    float* red = (float*)As;   // 128 rows x 32 slots = 16 KB (fits in 32 KB As)
    __syncthreads();           // all waves' MFMA LDS reads done -> reuse As
#pragma unroll
    for (int i = 0; i < 4; i++) {
#pragma unroll
      for (int r = 0; r < 4; r++) {
        const int rowl = wm * 64 + i * 16 + quad * 4 + r;
        const int row = m0 + rowl;
        float rp = 0.f;
#pragma unroll
        for (int j = 0; j < 4; j++) {
          const int col = n0 + wn * 64 + j * 16 + lm;
          float v = acc[i][j][r] + gate_b[col];
          float sig = 1.f / (1.f + __expf(-v));
          Gb[(size_t)row * DM + col] = f2b_bits(sig);
          rp += sig;
        }
        red[rowl * 32 + wn * 16 + lm] = rp;
      }
    }
    __syncthreads();
    if (tid < 128) {
      float s = 0.f;
#pragma unroll
      for (int t2 = 0; t2 < 32; t2++) s += red[tid * 32 + t2];
      atomicAdd(&gate_accum[m0 + tid], s);
    }
  } else {
#pragma unroll
    for (int i = 0; i < 4; i++) {
      const int rbase = m0 + wm * 64 + i * 16 + quad * 4;
#pragma unroll
      for (int j = 0; j < 4; j++) {
        const int col = n0 + wn * 64 + j * 16 + lm;
        const float bval = qkv_b[col];
#pragma unroll
        for (int r = 0; r < 4; r++) {
          const int row = rbase + r;
          const short bv = f2b_bits(acc[i][j][r] + bval);
          if (col < DM) {
            const int d = col;
            Qb[((size_t)(d >> 6) * T_SEQ + row) * DH + (d & 63)] = bv;
          } else if (col < 2 * DM) {
            const int d = col - DM;
            Kb[((size_t)(d >> 6) * T_SEQ + row) * DH + (d & 63)] = bv;
          } else {
            const int d = col - 2 * DM;
            Vb[((size_t)(d >> 6) * T_SEQ + row) * DH + (d & 63)] = bv;
            VbT[((size_t)(d >> 6) * DH + (d & 63)) * T_SEQ + row] = bv;
          }
        }
      }
    }
  }
}

// ---------------------------------------------------------------------------
// Pass A: per (h,c) RAW chunk sums, stored TRANSPOSED: SkvT[m][d]. Sk_c = col
// sums of gated K. Gating during staging.
// ---------------------------------------------------------------------------
__global__ __launch_bounds__(256, 2) void chunk_sum_mm(const short* __restrict__ Kb,
                                                       const short* __restrict__ Gb,
                                                       const float* __restrict__ ga,
                                                       const short* __restrict__ Vb,
                                                       float* __restrict__ SkvT,
                                                       float* __restrict__ Sk) {
  constexpr int STR = 68;
  __shared__ __align__(16) float Ks2[64 * STR];
  __shared__ __align__(16) float Vs2[64 * STR];
  const int b = blockIdx.x;
  const int h = b >> 5, c = b & 31;
  const int tid = threadIdx.x;
  const int ty = tid >> 4, tx = tid & 15;
  const int d0 = ty * 4, m0 = tx * 4;
  const int t0 = c * CHUNK;
  const size_t cb = ((size_t)h * T_SEQ + t0) * DH;
#pragma unroll
  for (int p = 0; p < 4; p++) {
    int f = p * 256 + tid, row = f >> 4, seg = (f & 15) * 4;
    const int t = t0 + row;
    short4v kr = *(const short4v*)&Kb[cb + row * 64 + seg];
    short4v gr = *(const short4v*)&Gb[(size_t)t * DM + h * 64 + seg];
    short4v vr = *(const short4v*)&Vb[cb + row * 64 + seg];
    const float inv = 1.f / (ga[t] * (1.f / DM) + 1e-5f);
    f32x4 kgv, vv;
#pragma unroll
    for (int e = 0; e < 4; e++) {
      kgv[e] = gelu1(b2f(kr[e]), b2f(gr[e]), inv);
      vv[e] = b2f(vr[e]);
    }
    *(f32x4*)&Ks2[row * STR + seg] = kgv;
    *(f32x4*)&Vs2[row * STR + seg] = vv;
  }
  __syncthreads();
  float acc[4][4] = {};
#pragma unroll 4
  for (int s = 0; s < 64; s++) {
    f32x4 kf = *(const f32x4*)&Ks2[s * STR + d0];
    f32x4 vf = *(const f32x4*)&Vs2[s * STR + m0];
#pragma unroll
    for (int i = 0; i < 4; i++)
#pragma unroll
      for (int j = 0; j < 4; j++) acc[i][j] += kf[i] * vf[j];
  }
  float* outp = SkvT + (size_t)b * 4096;
  // transposed store: SkvT[m][d] = acc[d][m]
#pragma unroll
  for (int i = 0; i < 4; i++)
#pragma unroll
    for (int j = 0; j < 4; j++)
      outp[(m0 + j) * 64 + (d0 + i)] = acc[i][j];
  if (tid < 64) {
    float ss = 0.f;
#pragma unroll 4
    for (int s = 0; s < 64; s++) ss += Ks2[s * STR + tid];
    Sk[b * 64 + tid] = ss;
  }
}

// ---------------------------------------------------------------------------
// Pass B: exclusive prefix over chunks (elementwise, layout-agnostic).
// ---------------------------------------------------------------------------
__global__ __launch_bounds__(256) void scan_excl(float* __restrict__ Skv,
                                                 float* __restrict__ Sk) {
  const int bid = blockIdx.x, tid = threadIdx.x;
  if (bid < 256) {
    const int id = bid * 256 + tid;
    const int h = id >> 12, e = id & 4095;
    float* base = Skv + (size_t)h * NCHUNK * 4096 + e;
    float v[NCHUNK];
#pragma unroll
    for (int c = 0; c < NCHUNK; c++) v[c] = base[(size_t)c * 4096];
    float run = 0.f;
#pragma unroll
    for (int c = 0; c < NCHUNK; c++) {
      float t = v[c];
      base[(size_t)c * 4096] = run;
      run += t;
    }
  } else {
    const int id = (bid - 256) * 256 + tid;
    const int h = id >> 6, e = id & 63;
    float* base = Sk + (size_t)h * NCHUNK * 64 + e;
    float v[NCHUNK];
#pragma unroll
    for (int c = 0; c < NCHUNK; c++) v[c] = base[c * 64];
    float run = 0.f;
#pragma unroll
    for (int c = 0; c < NCHUNK; c++) {
      float t = v[c];
      base[c * 64] = run;
      run += t;
    }
  }
}

// ---------------------------------------------------------------------------
// Pass C (MFMA): per (h,c), 4 waves.
//   S = Qg.Kg^T; O^T = P^T.Qg^T + V^T.S^T; den from masked-S rowsum + q.skp.
// R13: invden dot product parallelized across all 256 threads.
// ---------------------------------------------------------------------------
__global__ __launch_bounds__(256, 2) void attn_mfma(const short* __restrict__ Qb,
                                                    const short* __restrict__ Kb,
                                                    const short* __restrict__ Gb,
                                                    const float* __restrict__ ga,
                                                    const short* __restrict__ VbT,
                                                    const float* __restrict__ SkvT,
                                                    const float* __restrict__ Sk,
                                                    bf16* __restrict__ O) {
  constexpr int STR = 72;
  __shared__ __align__(16) short Qs[64 * STR];
  __shared__ __align__(16) short Ks[64 * STR];
  __shared__ __align__(16) short Vt[64 * STR];
  __shared__ __align__(16) short Pt[64 * STR];
  __shared__ __align__(16) short SL[64 * STR];
  __shared__ float denp[64], invden[64], skp[64];
  const int b = blockIdx.x;
  const int h = b >> 5, c = b & 31;
  const int tid = threadIdx.x;
  const int wid = tid >> 6, lane = tid & 63;
  const int lm = lane & 15, quad = lane >> 4;
  const int t0 = c * CHUNK;
  const size_t cb = ((size_t)h * T_SEQ + t0) * DH;
  const float* Pg = SkvT + (size_t)b * 4096;

#pragma unroll
  for (int p = 0; p < 4; p++) {
    const int f = p * 256 + tid, row = f >> 4, seg = (f & 15) * 4;
    const int t = t0 + row;
    short4v qr = *(const short4v*)&Qb[cb + row * 64 + seg];
    short4v kr = *(const short4v*)&Kb[cb + row * 64 + seg];
    short4v gr = *(const short4v*)&Gb[(size_t)t * DM + h * 64 + seg];
    short4v vtr = *(const short4v*)&VbT[((size_t)h * DH + row) * T_SEQ + t0 + seg];
    f32x4 pr = *(const f32x4*)&Pg[row * 64 + seg];
    const float inv = 1.f / (ga[t] * (1.f / DM) + 1e-5f);
    short4v qs, ks, ps;
#pragma unroll
    for (int e = 0; e < 4; e++) {
      qs[e] = f2b_bits(gelu1(b2f(qr[e]), b2f(gr[e]), inv));
      ks[e] = f2b_bits(gelu1(b2f(kr[e]), b2f(gr[e]), inv));
      ps[e] = f2b_bits(pr[e]);
    }
    *(short4v*)&Qs[row * STR + seg] = qs;
    *(short4v*)&Ks[row * STR + seg] = ks;
    *(short4v*)&Vt[row * STR + seg] = vtr;
    *(short4v*)&Pt[row * STR + seg] = ps;
  }
  if (tid < 64) skp[tid] = Sk[b * 64 + tid];
  __syncthreads();  // B1

  f32x4 zero = {0.f, 0.f, 0.f, 0.f};
  // ---- S = Qg.Kg^T ----
  short8 aq[2];
#pragma unroll
  for (int ks = 0; ks < 2; ks++)
    aq[ks] = *(const short8*)&Qs[(wid * 16 + lm) * STR + ks * 32 + quad * 8];
  f32x4 accs[4];
#pragma unroll
  for (int j = 0; j < 4; j++) accs[j] = zero;
#pragma unroll
  for (int j = 0; j < 4; j++)
#pragma unroll
    for (int ks = 0; ks < 2; ks++) {
      short8 bk = *(const short8*)&Ks[(j * 16 + lm) * STR + ks * 32 + quad * 8];
      accs[j] = __builtin_amdgcn_mfma_f32_16x16x32_bf16(aq[ks], bk, accs[j], 0, 0, 0);
    }
  float rowpart[4] = {0.f, 0.f, 0.f, 0.f};
#pragma unroll
  for (int j = 0; j < 4; j++) {
    const int s = j * 16 + lm;
#pragma unroll
    for (int r = 0; r < 4; r++) {
      const int t = wid * 16 + quad * 4 + r;
      float v = (s <= t) ? accs[j][r] : 0.f;
      accs[j][r] = v;
      rowpart[r] += v;
    }
  }
#pragma unroll
  for (int msk = 1; msk < 16; msk <<= 1)
#pragma unroll
    for (int r = 0; r < 4; r++) rowpart[r] += __shfl_xor(rowpart[r], msk, 64);
  if (lm == 0)
#pragma unroll
    for (int r = 0; r < 4; r++) denp[wid * 16 + quad * 4 + r] = rowpart[r];
#pragma unroll
  for (int j = 0; j < 4; j++)
#pragma unroll
    for (int r = 0; r < 4; r++)
      SL[(wid * 16 + quad * 4 + r) * STR + j * 16 + lm] = f2b_bits(accs[j][r]);

  // ---- O1^T = P^T.Qg^T ----
  f32x4 acco[4];
#pragma unroll
  for (int j = 0; j < 4; j++) acco[j] = zero;
  short8 ap[2];
#pragma unroll
  for (int ks = 0; ks < 2; ks++)
    ap[ks] = *(const short8*)&Pt[(wid * 16 + lm) * STR + ks * 32 + quad * 8];
#pragma unroll
  for (int j = 0; j < 4; j++)
#pragma unroll
    for (int ks = 0; ks < 2; ks++) {
      short8 bq = *(const short8*)&Qs[(j * 16 + lm) * STR + ks * 32 + quad * 8];
      acco[j] = __builtin_amdgcn_mfma_f32_16x16x32_bf16(ap[ks], bq, acco[j], 0, 0, 0);
    }
  __syncthreads();  // B2: SL + denp complete

  {
    // all 256 threads: row = tid>>2, part = tid&3 covers 16 d each
    const int row = tid >> 2, part = tid & 3;
    float s = 0.f;
#pragma unroll
    for (int dd = 0; dd < 16; dd++) {
      const int d = part * 16 + dd;
      s += b2f(Qs[row * STR + d]) * skp[d];
    }
    s += __shfl_xor(s, 1, 64);
    s += __shfl_xor(s, 2, 64);
    if (part == 0) invden[row] = 1.f / (1e-5f + denp[row] + s);
  }

  // ---- O2^T += V^T.S^T ----
  short8 av[2];
#pragma unroll
  for (int ks = 0; ks < 2; ks++)
    av[ks] = *(const short8*)&Vt[(wid * 16 + lm) * STR + ks * 32 + quad * 8];
#pragma unroll
  for (int j = 0; j < 4; j++)
#pragma unroll
    for (int ks = 0; ks < 2; ks++) {
      short8 bs = *(const short8*)&SL[(j * 16 + lm) * STR + ks * 32 + quad * 8];
      acco[j] = __builtin_amdgcn_mfma_f32_16x16x32_bf16(av[ks], bs, acco[j], 0, 0, 0);
    }
  __syncthreads();  // B3: invden ready

#pragma unroll
  for (int j = 0; j < 4; j++) {
    const int t = j * 16 + lm;
    const float idv = invden[t];
    short4v ov;
#pragma unroll
    for (int r = 0; r < 4; r++) ov[r] = f2b_bits(acco[j][r] * idv);
    *(short4v*)&((short*)O)[(size_t)(t0 + t) * DM + h * 64 + wid * 16 + quad * 4] = ov;
  }
}

// ---------------------------------------------------------------------------
// Proj GEMM: tile 64x64, grid (16 n-fast, 32 m) = 512 blocks (2/CU).
// R24 (confirmed win): BK=256, 4 K-steps, LDS 2x32KB. Swizzle for 512B rows
// (32 chunks of 16B): slot s of row r holds chunk s^(r&31). Staging: 8
// rows/issue, XOR per-issue: row = it*8 + (tid>>5), source chunk
// (tid&31)^(row&31). Read slot (sec*4+quad)^(row&31).
// ---------------------------------------------------------------------------
__global__ __launch_bounds__(256) void gemm_proj(const bf16* __restrict__ A,
                                                 const bf16* __restrict__ W,
                                                 const float* __restrict__ bias,
                                                 float* __restrict__ Cout) {
  constexpr int K = 1024;
  __shared__ __align__(16) short As[64 * 256];   // 32 KB
  __shared__ __align__(16) short Bs[64 * 256];   // 32 KB

  const int tid = threadIdx.x;
  const int wid = tid >> 6, lane = tid & 63;
  const int wm = wid >> 1, wn = wid & 1;   // wave tile 32x32
  const int lm = lane & 15, quad = lane >> 4;

  const int n0 = blockIdx.x * 64;
  const int m0 = blockIdx.y * 64;
  const short* Ag = (const short*)A;
  const short* Wg = (const short*)W;

  // staging: per issue, 256 lanes x 16 B = 4 KB = 8 rows x 512 B.
  const int grow = tid >> 5;        // 0..7: row within issue
  const int lchunk = tid & 31;      // LDS slot within row

  f32x4 zero = {0.f, 0.f, 0.f, 0.f};
  f32x4 acc[2][2];
#pragma unroll
  for (int i = 0; i < 2; i++)
#pragma unroll
    for (int j = 0; j < 2; j++) acc[i][j] = zero;

  for (int kb = 0; kb < K; kb += 256) {
    __syncthreads();
#pragma unroll
    for (int it = 0; it < 8; it++) {
      const int row = it * 8 + grow;
      const int swq = (lchunk ^ (row & 31)) * 8;   // source chunk for linear slot
      gload16(&Ag[(size_t)(m0 + row) * K + kb + swq], &As[it * 2048 + wid * 512]);
      gload16(&Wg[(size_t)(n0 + row) * K + kb + swq], &Bs[it * 2048 + wid * 512]);
    }
    __syncthreads();
#pragma unroll
    for (int sec = 0; sec < 8; sec++) {
      short8 afr[2], bfr[2];
#pragma unroll
      for (int i = 0; i < 2; i++) {
        const int row = wm * 32 + i * 16 + lm;
        const int slot8 = (((sec * 4 + quad) ^ (row & 31)) * 8);
        afr[i] = *(const short8*)&As[row * 256 + slot8];
      }
#pragma unroll
      for (int j = 0; j < 2; j++) {
        const int row = wn * 32 + j * 16 + lm;
        const int slot8 = (((sec * 4 + quad) ^ (row & 31)) * 8);
        bfr[j] = *(const short8*)&Bs[row * 256 + slot8];
      }
#pragma unroll
      for (int i = 0; i < 2; i++)
#pragma unroll
        for (int j = 0; j < 2; j++)
          acc[i][j] = __builtin_amdgcn_mfma_f32_16x16x32_bf16(afr[i], bfr[j], acc[i][j], 0, 0, 0);
    }
  }
#pragma unroll
  for (int i = 0; i < 2; i++) {
    const int rbase = m0 + wm * 32 + i * 16 + quad * 4;
#pragma unroll
    for (int j = 0; j < 2; j++) {
      const int col = n0 + wn * 32 + j * 16 + lm;
      const float bval = bias[col];
#pragma unroll
      for (int r = 0; r < 4; r++)
        Cout[(size_t)(rbase + r) * DM + col] = acc[i][j][r] + bval;
    }
  }
}

// ---------------------------------------------------------------------------
extern "C" void kernel_launch(void* const* d_in, const int* in_sizes, int n_in,
                              void* d_out, int out_size, void* d_ws, size_t ws_size,
                              hipStream_t stream) {
  (void)in_sizes; (void)n_in; (void)out_size; (void)ws_size;
  const float* x      = (const float*)d_in[0];
  const float* ln_g   = (const float*)d_in[1];
  const float* ln_b   = (const float*)d_in[2];
  const float* qkv_w  = (const float*)d_in[3];
  const float* qkv_b  = (const float*)d_in[4];
  const float* gate_w = (const float*)d_in[5];
  const float* gate_b = (const float*)d_in[6];
  const float* proj_w = (const float*)d_in[7];
  const float* proj_b = (const float*)d_in[8];
  float* out = (float*)d_out;

  char* ws = (char*)d_ws;
  size_t off = 0;
  auto alloc = [&](size_t bytes) {
    void* p = ws + off;
    off += (bytes + 255) & ~(size_t)255;
    return p;
  };
  bf16*  xn       = (bf16*)alloc((size_t)T_SEQ * DM * 2);
  bf16*  xbf      = (bf16*)alloc((size_t)T_SEQ * DM * 2);
  bf16*  wqkv     = (bf16*)alloc((size_t)3 * DM * DM * 2);
  bf16*  wgate    = (bf16*)alloc((size_t)DM * DM * 2);
  bf16*  wproj    = (bf16*)alloc((size_t)DM * DM * 2);
  short* Gb       = (short*)alloc((size_t)T_SEQ * DM * 2);
  float* gate_accum = (float*)alloc((size_t)T_SEQ * 4);
  short* Qb       = (short*)alloc((size_t)T_SEQ * DM * 2);
  short* Kb       = (short*)alloc((size_t)T_SEQ * DM * 2);
  short* Vb       = (short*)alloc((size_t)T_SEQ * DM * 2);
  short* VbT      = (short*)alloc((size_t)T_SEQ * DM * 2);
  bf16*  Obuf     = (bf16*)alloc((size_t)T_SEQ * DM * 2);
  float* SkvT     = (float*)alloc((size_t)NH * NCHUNK * 4096 * 4);
  float* Sk       = (float*)alloc((size_t)NH * NCHUNK * 64 * 4);

  prep_kernel<<<T_SEQ + PREP_WBLOCKS, 256, 0, stream>>>(
      x, ln_g, ln_b, qkv_w, gate_w, proj_w, xn, xbf, wqkv, wgate, wproj, gate_accum);
  gemm_gateqkv<<<dim3(32, 16), 256, 0, stream>>>(xbf, xn, wgate, wqkv, gate_b, qkv_b,
                                                 Gb, gate_accum, Qb, Kb, Vb, VbT);
  chunk_sum_mm<<<NH * NCHUNK, 256, 0, stream>>>(Kb, Gb, gate_accum, Vb, SkvT, Sk);
  scan_excl<<<260, 256, 0, stream>>>(SkvT, Sk);
  attn_mfma<<<NH * NCHUNK, 256, 0, stream>>>(Qb, Kb, Gb, gate_accum, VbT, SkvT, Sk, Obuf);
  gemm_proj<<<dim3(16, 32), 256, 0, stream>>>(Obuf, wproj, proj_b, out);
}

// Round 16
// 154.157 us; speedup vs baseline: 1.5694x; 1.0079x over previous
//
#include <hip/hip_runtime.h>
#include <hip/hip_bf16.h>
#include <math.h>

#define T_SEQ 2048
#define DM 1024
#define NH 16
#define DH 64
#define CHUNK 64
#define NCHUNK (T_SEQ / CHUNK)   // 32

typedef __hip_bfloat16 bf16;
typedef __attribute__((ext_vector_type(8))) short short8;
typedef __attribute__((ext_vector_type(4))) short short4v;
typedef __attribute__((ext_vector_type(4))) float f32x4;

static __device__ __forceinline__ short f2b_bits(float f) {
  bf16 t = __float2bfloat16(f);
  short s;
  __builtin_memcpy(&s, &t, 2);
  return s;
}
static __device__ __forceinline__ float b2f(short s) {
  unsigned int u = ((unsigned int)(unsigned short)s) << 16;
  float f;
  __builtin_memcpy(&f, &u, 4);
  return f;
}
// gated ELU+1: elu(x)+1 = x>0 ? x+1 : exp(x)
static __device__ __forceinline__ float gelu1(float raw, float gate, float inv) {
  float x = raw * gate * inv;
  return x > 0.f ? x + 1.f : __expf(x);
}
static __device__ __forceinline__ void gload16(const void* g, void* l) {
  __builtin_amdgcn_global_load_lds((const __attribute__((address_space(1))) void*)g,
                                   (__attribute__((address_space(3))) void*)l, 16, 0, 0);
}

// ---------------------------------------------------------------------------
// prep: blocks 0..2047 = LayerNorm rows (blocks 0..7 also zero gate_accum);
//       blocks 2048..  = fp32->bf16 weight conversion (qkv|gate|proj).
// ---------------------------------------------------------------------------
#define PREP_WBLOCKS (5 * DM * DM / 4 / 256)   // 5120
__global__ __launch_bounds__(256) void prep_kernel(
    const float* __restrict__ x, const float* __restrict__ g,
    const float* __restrict__ b, const float* __restrict__ qkv_w,
    const float* __restrict__ gate_w, const float* __restrict__ proj_w,
    bf16* __restrict__ xn, bf16* __restrict__ xbf,
    bf16* __restrict__ wqkv, bf16* __restrict__ wgate, bf16* __restrict__ wproj,
    float* __restrict__ gate_accum) {
  const int blk = blockIdx.x;
  if (blk < T_SEQ) {
    const int row = blk;
    if (row < 8) gate_accum[row * 256 + threadIdx.x] = 0.f;
    const float* xr = x + (size_t)row * DM;
    float vals[4];
    float s = 0.f, s2 = 0.f;
#pragma unroll
    for (int i = 0; i < 4; i++) {
      float v = xr[threadIdx.x + i * 256];
      vals[i] = v;
      s += v;
      s2 += v * v;
    }
#pragma unroll
    for (int m = 1; m < 64; m <<= 1) {
      s += __shfl_xor(s, m, 64);
      s2 += __shfl_xor(s2, m, 64);
    }
    __shared__ float red[8];
    const int wid = threadIdx.x >> 6;
    if ((threadIdx.x & 63) == 0) {
      red[wid] = s;
      red[4 + wid] = s2;
    }
    __syncthreads();
    s = red[0] + red[1] + red[2] + red[3];
    s2 = red[4] + red[5] + red[6] + red[7];
    const float mean = s * (1.f / DM);
    const float var = s2 * (1.f / DM) - mean * mean;
    const float rstd = rsqrtf(var + 1e-5f);
#pragma unroll
    for (int i = 0; i < 4; i++) {
      int idx = threadIdx.x + i * 256;
      float v = (vals[i] - mean) * rstd * g[idx] + b[idx];
      xn[(size_t)row * DM + idx] = __float2bfloat16(v);
      xbf[(size_t)row * DM + idx] = __float2bfloat16(vals[i]);
    }
  } else {
    constexpr int NQ = 3 * DM * DM / 4, NS = DM * DM / 4;
    int i = (blk - T_SEQ) * 256 + threadIdx.x;
    const float* src;
    bf16* dst;
    int j;
    if (i < NQ) { src = qkv_w; dst = wqkv; j = i; }
    else if (i < NQ + NS) { src = gate_w; dst = wgate; j = i - NQ; }
    else { src = proj_w; dst = wproj; j = i - NQ - NS; }
    float4 v = ((const float4*)src)[j];
    short4v sv;
    sv.x = f2b_bits(v.x); sv.y = f2b_bits(v.y); sv.z = f2b_bits(v.z); sv.w = f2b_bits(v.w);
    *(short4v*)&dst[j * 4] = sv;
  }
}

// ---------------------------------------------------------------------------
// Fused gate+qkv GEMM. R23 (confirmed win): 128x128 tile, BK=128, 8 K-steps.
// Per-K-step barrier drain is a fixed ~800cy cost (R19 PMC arithmetic);
// halving step count 16->8 was the confirmed win (R22 159.5 -> R23 153.3).
// LDS 2x32KB=64KB, 2 blocks/CU (grid-capped). Swizzle for 256B rows:
// slot s of row r holds chunk s^(r&15).
// ---------------------------------------------------------------------------
__global__ __launch_bounds__(256) void gemm_gateqkv(
    const bf16* __restrict__ xbf, const bf16* __restrict__ xn,
    const bf16* __restrict__ wg, const bf16* __restrict__ wq,
    const float* __restrict__ gate_b, const float* __restrict__ qkv_b,
    short* __restrict__ Gb, float* __restrict__ gate_accum,
    short* __restrict__ Qb, short* __restrict__ Kb, short* __restrict__ Vb,
    short* __restrict__ VbT) {
  constexpr int K = 1024;
  __shared__ __align__(16) short As[128 * 128];   // 32 KB
  __shared__ __align__(16) short Bs[128 * 128];   // 32 KB

  const int tid = threadIdx.x;
  const int wid = tid >> 6, lane = tid & 63;
  const int wm = wid >> 1, wn = wid & 1;   // wave tile 64(m) x 64(n)
  const int lm = lane & 15, quad = lane >> 4;

  const int nt = blockIdx.x;
  const bool isGate = nt < 8;
  const int m0 = blockIdx.y * 128;
  const int n0 = (isGate ? nt : nt - 8) * 128;
  const short* Ag = (const short*)(isGate ? xbf : xn);
  const short* Wg = (const short*)(isGate ? wg : wq);

  f32x4 zero = {0.f, 0.f, 0.f, 0.f};
  f32x4 acc[4][4];
#pragma unroll
  for (int i = 0; i < 4; i++)
#pragma unroll
    for (int j = 0; j < 4; j++) acc[i][j] = zero;

  // staging: per issue, 256 lanes x 16 B = 4 KB = 16 rows x 256 B.
  const int grow = tid >> 4;
  const int swq = ((tid & 15) ^ ((tid >> 4) & 15)) * 8;

  for (int kb = 0; kb < K; kb += 128) {
    __syncthreads();
#pragma unroll
    for (int it = 0; it < 8; it++) {
      const int row = it * 16 + grow;
      gload16(&Ag[(size_t)(m0 + row) * K + kb + swq], &As[it * 2048 + wid * 512]);
      gload16(&Wg[(size_t)(n0 + row) * K + kb + swq], &Bs[it * 2048 + wid * 512]);
    }
    __syncthreads();
#pragma unroll
    for (int sec = 0; sec < 4; sec++) {
      const int slot8 = (((sec * 4 + quad) ^ lm) * 8);
      short8 afr[4], bfr[4];
#pragma unroll
      for (int i = 0; i < 4; i++)
        afr[i] = *(const short8*)&As[(wm * 64 + i * 16 + lm) * 128 + slot8];
#pragma unroll
      for (int j = 0; j < 4; j++)
        bfr[j] = *(const short8*)&Bs[(wn * 64 + j * 16 + lm) * 128 + slot8];
#pragma unroll
      for (int i = 0; i < 4; i++)
#pragma unroll
        for (int j = 0; j < 4; j++)
          acc[i][j] = __builtin_amdgcn_mfma_f32_16x16x32_bf16(afr[i], bfr[j], acc[i][j], 0, 0, 0);
    }
  }

  // epilogue: C/D layout col = lane&15, row = quad*4 + r
  if (isGate) {
    float* red = (float*)As;   // 128 rows x 32 slots = 16 KB (fits in 32 KB As)
    __syncthreads();           // all waves' MFMA LDS reads done -> reuse As
#pragma unroll
    for (int i = 0; i < 4; i++) {
#pragma unroll
      for (int r = 0; r < 4; r++) {
        const int rowl = wm * 64 + i * 16 + quad * 4 + r;
        const int row = m0 + rowl;
        float rp = 0.f;
#pragma unroll
        for (int j = 0; j < 4; j++) {
          const int col = n0 + wn * 64 + j * 16 + lm;
          float v = acc[i][j][r] + gate_b[col];
          float sig = 1.f / (1.f + __expf(-v));
          Gb[(size_t)row * DM + col] = f2b_bits(sig);
          rp += sig;
        }
        red[rowl * 32 + wn * 16 + lm] = rp;
      }
    }
    __syncthreads();
    if (tid < 128) {
      float s = 0.f;
#pragma unroll
      for (int t2 = 0; t2 < 32; t2++) s += red[tid * 32 + t2];
      atomicAdd(&gate_accum[m0 + tid], s);
    }
  } else {
#pragma unroll
    for (int i = 0; i < 4; i++) {
      const int rbase = m0 + wm * 64 + i * 16 + quad * 4;
#pragma unroll
      for (int j = 0; j < 4; j++) {
        const int col = n0 + wn * 64 + j * 16 + lm;
        const float bval = qkv_b[col];
#pragma unroll
        for (int r = 0; r < 4; r++) {
          const int row = rbase + r;
          const short bv = f2b_bits(acc[i][j][r] + bval);
          if (col < DM) {
            const int d = col;
            Qb[((size_t)(d >> 6) * T_SEQ + row) * DH + (d & 63)] = bv;
          } else if (col < 2 * DM) {
            const int d = col - DM;
            Kb[((size_t)(d >> 6) * T_SEQ + row) * DH + (d & 63)] = bv;
          } else {
            const int d = col - 2 * DM;
            Vb[((size_t)(d >> 6) * T_SEQ + row) * DH + (d & 63)] = bv;
            VbT[((size_t)(d >> 6) * DH + (d & 63)) * T_SEQ + row] = bv;
          }
        }
      }
    }
  }
}

// ---------------------------------------------------------------------------
// Pass A: per (h,c) RAW chunk sums, stored TRANSPOSED: SkvT[m][d]. Sk_c = col
// sums of gated K. Gating during staging.
// ---------------------------------------------------------------------------
__global__ __launch_bounds__(256, 2) void chunk_sum_mm(const short* __restrict__ Kb,
                                                       const short* __restrict__ Gb,
                                                       const float* __restrict__ ga,
                                                       const short* __restrict__ Vb,
                                                       float* __restrict__ SkvT,
                                                       float* __restrict__ Sk) {
  constexpr int STR = 68;
  __shared__ __align__(16) float Ks2[64 * STR];
  __shared__ __align__(16) float Vs2[64 * STR];
  const int b = blockIdx.x;
  const int h = b >> 5, c = b & 31;
  const int tid = threadIdx.x;
  const int ty = tid >> 4, tx = tid & 15;
  const int d0 = ty * 4, m0 = tx * 4;
  const int t0 = c * CHUNK;
  const size_t cb = ((size_t)h * T_SEQ + t0) * DH;
#pragma unroll
  for (int p = 0; p < 4; p++) {
    int f = p * 256 + tid, row = f >> 4, seg = (f & 15) * 4;
    const int t = t0 + row;
    short4v kr = *(const short4v*)&Kb[cb + row * 64 + seg];
    short4v gr = *(const short4v*)&Gb[(size_t)t * DM + h * 64 + seg];
    short4v vr = *(const short4v*)&Vb[cb + row * 64 + seg];
    const float inv = 1.f / (ga[t] * (1.f / DM) + 1e-5f);
    f32x4 kgv, vv;
#pragma unroll
    for (int e = 0; e < 4; e++) {
      kgv[e] = gelu1(b2f(kr[e]), b2f(gr[e]), inv);
      vv[e] = b2f(vr[e]);
    }
    *(f32x4*)&Ks2[row * STR + seg] = kgv;
    *(f32x4*)&Vs2[row * STR + seg] = vv;
  }
  __syncthreads();
  float acc[4][4] = {};
#pragma unroll 4
  for (int s = 0; s < 64; s++) {
    f32x4 kf = *(const f32x4*)&Ks2[s * STR + d0];
    f32x4 vf = *(const f32x4*)&Vs2[s * STR + m0];
#pragma unroll
    for (int i = 0; i < 4; i++)
#pragma unroll
      for (int j = 0; j < 4; j++) acc[i][j] += kf[i] * vf[j];
  }
  float* outp = SkvT + (size_t)b * 4096;
  // transposed store: SkvT[m][d] = acc[d][m]
#pragma unroll
  for (int i = 0; i < 4; i++)
#pragma unroll
    for (int j = 0; j < 4; j++)
      outp[(m0 + j) * 64 + (d0 + i)] = acc[i][j];
  if (tid < 64) {
    float ss = 0.f;
#pragma unroll 4
    for (int s = 0; s < 64; s++) ss += Ks2[s * STR + tid];
    Sk[b * 64 + tid] = ss;
  }
}

// ---------------------------------------------------------------------------
// Pass B: exclusive prefix over chunks (elementwise, layout-agnostic).
// ---------------------------------------------------------------------------
__global__ __launch_bounds__(256) void scan_excl(float* __restrict__ Skv,
                                                 float* __restrict__ Sk) {
  const int bid = blockIdx.x, tid = threadIdx.x;
  if (bid < 256) {
    const int id = bid * 256 + tid;
    const int h = id >> 12, e = id & 4095;
    float* base = Skv + (size_t)h * NCHUNK * 4096 + e;
    float v[NCHUNK];
#pragma unroll
    for (int c = 0; c < NCHUNK; c++) v[c] = base[(size_t)c * 4096];
    float run = 0.f;
#pragma unroll
    for (int c = 0; c < NCHUNK; c++) {
      float t = v[c];
      base[(size_t)c * 4096] = run;
      run += t;
    }
  } else {
    const int id = (bid - 256) * 256 + tid;
    const int h = id >> 6, e = id & 63;
    float* base = Sk + (size_t)h * NCHUNK * 64 + e;
    float v[NCHUNK];
#pragma unroll
    for (int c = 0; c < NCHUNK; c++) v[c] = base[c * 64];
    float run = 0.f;
#pragma unroll
    for (int c = 0; c < NCHUNK; c++) {
      float t = v[c];
      base[c * 64] = run;
      run += t;
    }
  }
}

// ---------------------------------------------------------------------------
// Pass C (MFMA): per (h,c), 4 waves.
//   S = Qg.Kg^T; O^T = P^T.Qg^T + V^T.S^T; den from masked-S rowsum + q.skp.
// R13: invden dot product parallelized across all 256 threads.
// ---------------------------------------------------------------------------
__global__ __launch_bounds__(256, 2) void attn_mfma(const short* __restrict__ Qb,
                                                    const short* __restrict__ Kb,
                                                    const short* __restrict__ Gb,
                                                    const float* __restrict__ ga,
                                                    const short* __restrict__ VbT,
                                                    const float* __restrict__ SkvT,
                                                    const float* __restrict__ Sk,
                                                    bf16* __restrict__ O) {
  constexpr int STR = 72;
  __shared__ __align__(16) short Qs[64 * STR];
  __shared__ __align__(16) short Ks[64 * STR];
  __shared__ __align__(16) short Vt[64 * STR];
  __shared__ __align__(16) short Pt[64 * STR];
  __shared__ __align__(16) short SL[64 * STR];
  __shared__ float denp[64], invden[64], skp[64];
  const int b = blockIdx.x;
  const int h = b >> 5, c = b & 31;
  const int tid = threadIdx.x;
  const int wid = tid >> 6, lane = tid & 63;
  const int lm = lane & 15, quad = lane >> 4;
  const int t0 = c * CHUNK;
  const size_t cb = ((size_t)h * T_SEQ + t0) * DH;
  const float* Pg = SkvT + (size_t)b * 4096;

#pragma unroll
  for (int p = 0; p < 4; p++) {
    const int f = p * 256 + tid, row = f >> 4, seg = (f & 15) * 4;
    const int t = t0 + row;
    short4v qr = *(const short4v*)&Qb[cb + row * 64 + seg];
    short4v kr = *(const short4v*)&Kb[cb + row * 64 + seg];
    short4v gr = *(const short4v*)&Gb[(size_t)t * DM + h * 64 + seg];
    short4v vtr = *(const short4v*)&VbT[((size_t)h * DH + row) * T_SEQ + t0 + seg];
    f32x4 pr = *(const f32x4*)&Pg[row * 64 + seg];
    const float inv = 1.f / (ga[t] * (1.f / DM) + 1e-5f);
    short4v qs, ks, ps;
#pragma unroll
    for (int e = 0; e < 4; e++) {
      qs[e] = f2b_bits(gelu1(b2f(qr[e]), b2f(gr[e]), inv));
      ks[e] = f2b_bits(gelu1(b2f(kr[e]), b2f(gr[e]), inv));
      ps[e] = f2b_bits(pr[e]);
    }
    *(short4v*)&Qs[row * STR + seg] = qs;
    *(short4v*)&Ks[row * STR + seg] = ks;
    *(short4v*)&Vt[row * STR + seg] = vtr;
    *(short4v*)&Pt[row * STR + seg] = ps;
  }
  if (tid < 64) skp[tid] = Sk[b * 64 + tid];
  __syncthreads();  // B1

  f32x4 zero = {0.f, 0.f, 0.f, 0.f};
  // ---- S = Qg.Kg^T ----
  short8 aq[2];
#pragma unroll
  for (int ks = 0; ks < 2; ks++)
    aq[ks] = *(const short8*)&Qs[(wid * 16 + lm) * STR + ks * 32 + quad * 8];
  f32x4 accs[4];
#pragma unroll
  for (int j = 0; j < 4; j++) accs[j] = zero;
#pragma unroll
  for (int j = 0; j < 4; j++)
#pragma unroll
    for (int ks = 0; ks < 2; ks++) {
      short8 bk = *(const short8*)&Ks[(j * 16 + lm) * STR + ks * 32 + quad * 8];
      accs[j] = __builtin_amdgcn_mfma_f32_16x16x32_bf16(aq[ks], bk, accs[j], 0, 0, 0);
    }
  float rowpart[4] = {0.f, 0.f, 0.f, 0.f};
#pragma unroll
  for (int j = 0; j < 4; j++) {
    const int s = j * 16 + lm;
#pragma unroll
    for (int r = 0; r < 4; r++) {
      const int t = wid * 16 + quad * 4 + r;
      float v = (s <= t) ? accs[j][r] : 0.f;
      accs[j][r] = v;
      rowpart[r] += v;
    }
  }
#pragma unroll
  for (int msk = 1; msk < 16; msk <<= 1)
#pragma unroll
    for (int r = 0; r < 4; r++) rowpart[r] += __shfl_xor(rowpart[r], msk, 64);
  if (lm == 0)
#pragma unroll
    for (int r = 0; r < 4; r++) denp[wid * 16 + quad * 4 + r] = rowpart[r];
#pragma unroll
  for (int j = 0; j < 4; j++)
#pragma unroll
    for (int r = 0; r < 4; r++)
      SL[(wid * 16 + quad * 4 + r) * STR + j * 16 + lm] = f2b_bits(accs[j][r]);

  // ---- O1^T = P^T.Qg^T ----
  f32x4 acco[4];
#pragma unroll
  for (int j = 0; j < 4; j++) acco[j] = zero;
  short8 ap[2];
#pragma unroll
  for (int ks = 0; ks < 2; ks++)
    ap[ks] = *(const short8*)&Pt[(wid * 16 + lm) * STR + ks * 32 + quad * 8];
#pragma unroll
  for (int j = 0; j < 4; j++)
#pragma unroll
    for (int ks = 0; ks < 2; ks++) {
      short8 bq = *(const short8*)&Qs[(j * 16 + lm) * STR + ks * 32 + quad * 8];
      acco[j] = __builtin_amdgcn_mfma_f32_16x16x32_bf16(ap[ks], bq, acco[j], 0, 0, 0);
    }
  __syncthreads();  // B2: SL + denp complete

  {
    // all 256 threads: row = tid>>2, part = tid&3 covers 16 d each
    const int row = tid >> 2, part = tid & 3;
    float s = 0.f;
#pragma unroll
    for (int dd = 0; dd < 16; dd++) {
      const int d = part * 16 + dd;
      s += b2f(Qs[row * STR + d]) * skp[d];
    }
    s += __shfl_xor(s, 1, 64);
    s += __shfl_xor(s, 2, 64);
    if (part == 0) invden[row] = 1.f / (1e-5f + denp[row] + s);
  }

  // ---- O2^T += V^T.S^T ----
  short8 av[2];
#pragma unroll
  for (int ks = 0; ks < 2; ks++)
    av[ks] = *(const short8*)&Vt[(wid * 16 + lm) * STR + ks * 32 + quad * 8];
#pragma unroll
  for (int j = 0; j < 4; j++)
#pragma unroll
    for (int ks = 0; ks < 2; ks++) {
      short8 bs = *(const short8*)&SL[(j * 16 + lm) * STR + ks * 32 + quad * 8];
      acco[j] = __builtin_amdgcn_mfma_f32_16x16x32_bf16(av[ks], bs, acco[j], 0, 0, 0);
    }
  __syncthreads();  // B3: invden ready

#pragma unroll
  for (int j = 0; j < 4; j++) {
    const int t = j * 16 + lm;
    const float idv = invden[t];
    short4v ov;
#pragma unroll
    for (int r = 0; r < 4; r++) ov[r] = f2b_bits(acco[j][r] * idv);
    *(short4v*)&((short*)O)[(size_t)(t0 + t) * DM + h * 64 + wid * 16 + quad * 4] = ov;
  }
}

// ---------------------------------------------------------------------------
// Proj GEMM: tile 64x64, grid (16 n-fast, 32 m) = 512 blocks (2/CU).
// R24 (confirmed win): BK=256, 4 K-steps, LDS 2x32KB. Swizzle for 512B rows
// (32 chunks of 16B): slot s of row r holds chunk s^(r&31). Staging: 8
// rows/issue, XOR per-issue: row = it*8 + (tid>>5), source chunk
// (tid&31)^(row&31). Read slot (sec*4+quad)^(row&31).
// ---------------------------------------------------------------------------
__global__ __launch_bounds__(256) void gemm_proj(const bf16* __restrict__ A,
                                                 const bf16* __restrict__ W,
                                                 const float* __restrict__ bias,
                                                 float* __restrict__ Cout) {
  constexpr int K = 1024;
  __shared__ __align__(16) short As[64 * 256];   // 32 KB
  __shared__ __align__(16) short Bs[64 * 256];   // 32 KB

  const int tid = threadIdx.x;
  const int wid = tid >> 6, lane = tid & 63;
  const int wm = wid >> 1, wn = wid & 1;   // wave tile 32x32
  const int lm = lane & 15, quad = lane >> 4;

  const int n0 = blockIdx.x * 64;
  const int m0 = blockIdx.y * 64;
  const short* Ag = (const short*)A;
  const short* Wg = (const short*)W;

  // staging: per issue, 256 lanes x 16 B = 4 KB = 8 rows x 512 B.
  const int grow = tid >> 5;        // 0..7: row within issue
  const int lchunk = tid & 31;      // LDS slot within row

  f32x4 zero = {0.f, 0.f, 0.f, 0.f};
  f32x4 acc[2][2];
#pragma unroll
  for (int i = 0; i < 2; i++)
#pragma unroll
    for (int j = 0; j < 2; j++) acc[i][j] = zero;

  for (int kb = 0; kb < K; kb += 256) {
    __syncthreads();
#pragma unroll
    for (int it = 0; it < 8; it++) {
      const int row = it * 8 + grow;
      const int swq = (lchunk ^ (row & 31)) * 8;   // source chunk for linear slot
      gload16(&Ag[(size_t)(m0 + row) * K + kb + swq], &As[it * 2048 + wid * 512]);
      gload16(&Wg[(size_t)(n0 + row) * K + kb + swq], &Bs[it * 2048 + wid * 512]);
    }
    __syncthreads();
#pragma unroll
    for (int sec = 0; sec < 8; sec++) {
      short8 afr[2], bfr[2];
#pragma unroll
      for (int i = 0; i < 2; i++) {
        const int row = wm * 32 + i * 16 + lm;
        const int slot8 = (((sec * 4 + quad) ^ (row & 31)) * 8);
        afr[i] = *(const short8*)&As[row * 256 + slot8];
      }
#pragma unroll
      for (int j = 0; j < 2; j++) {
        const int row = wn * 32 + j * 16 + lm;
        const int slot8 = (((sec * 4 + quad) ^ (row & 31)) * 8);
        bfr[j] = *(const short8*)&Bs[row * 256 + slot8];
      }
#pragma unroll
      for (int i = 0; i < 2; i++)
#pragma unroll
        for (int j = 0; j < 2; j++)
          acc[i][j] = __builtin_amdgcn_mfma_f32_16x16x32_bf16(afr[i], bfr[j], acc[i][j], 0, 0, 0);
    }
  }
#pragma unroll
  for (int i = 0; i < 2; i++) {
    const int rbase = m0 + wm * 32 + i * 16 + quad * 4;
#pragma unroll
    for (int j = 0; j < 2; j++) {
      const int col = n0 + wn * 32 + j * 16 + lm;
      const float bval = bias[col];
#pragma unroll
      for (int r = 0; r < 4; r++)
        Cout[(size_t)(rbase + r) * DM + col] = acc[i][j][r] + bval;
    }
  }
}

// ---------------------------------------------------------------------------
extern "C" void kernel_launch(void* const* d_in, const int* in_sizes, int n_in,
                              void* d_out, int out_size, void* d_ws, size_t ws_size,
                              hipStream_t stream) {
  (void)in_sizes; (void)n_in; (void)out_size; (void)ws_size;
  const float* x      = (const float*)d_in[0];
  const float* ln_g   = (const float*)d_in[1];
  const float* ln_b   = (const float*)d_in[2];
  const float* qkv_w  = (const float*)d_in[3];
  const float* qkv_b  = (const float*)d_in[4];
  const float* gate_w = (const float*)d_in[5];
  const float* gate_b = (const float*)d_in[6];
  const float* proj_w = (const float*)d_in[7];
  const float* proj_b = (const float*)d_in[8];
  float* out = (float*)d_out;

  char* ws = (char*)d_ws;
  size_t off = 0;
  auto alloc = [&](size_t bytes) {
    void* p = ws + off;
    off += (bytes + 255) & ~(size_t)255;
    return p;
  };
  bf16*  xn       = (bf16*)alloc((size_t)T_SEQ * DM * 2);
  bf16*  xbf      = (bf16*)alloc((size_t)T_SEQ * DM * 2);
  bf16*  wqkv     = (bf16*)alloc((size_t)3 * DM * DM * 2);
  bf16*  wgate    = (bf16*)alloc((size_t)DM * DM * 2);
  bf16*  wproj    = (bf16*)alloc((size_t)DM * DM * 2);
  short* Gb       = (short*)alloc((size_t)T_SEQ * DM * 2);
  float* gate_accum = (float*)alloc((size_t)T_SEQ * 4);
  short* Qb       = (short*)alloc((size_t)T_SEQ * DM * 2);
  short* Kb       = (short*)alloc((size_t)T_SEQ * DM * 2);
  short* Vb       = (short*)alloc((size_t)T_SEQ * DM * 2);
  short* VbT      = (short*)alloc((size_t)T_SEQ * DM * 2);
  bf16*  Obuf     = (bf16*)alloc((size_t)T_SEQ * DM * 2);
  float* SkvT     = (float*)alloc((size_t)NH * NCHUNK * 4096 * 4);
  float* Sk       = (float*)alloc((size_t)NH * NCHUNK * 64 * 4);

  prep_kernel<<<T_SEQ + PREP_WBLOCKS, 256, 0, stream>>>(
      x, ln_g, ln_b, qkv_w, gate_w, proj_w, xn, xbf, wqkv, wgate, wproj, gate_accum);
  gemm_gateqkv<<<dim3(32, 16), 256, 0, stream>>>(xbf, xn, wgate, wqkv, gate_b, qkv_b,
                                                 Gb, gate_accum, Qb, Kb, Vb, VbT);
  chunk_sum_mm<<<NH * NCHUNK, 256, 0, stream>>>(Kb, Gb, gate_accum, Vb, SkvT, Sk);
  scan_excl<<<260, 256, 0, stream>>>(SkvT, Sk);
  attn_mfma<<<NH * NCHUNK, 256, 0, stream>>>(Qb, Kb, Gb, gate_accum, VbT, SkvT, Sk, Obuf);
  gemm_proj<<<dim3(16, 32), 256, 0, stream>>>(Obuf, wproj, proj_b, out);
}